// Round 3
// baseline (622.020 us; speedup 1.0000x reference)
//
#include <hip/hip_runtime.h>

// GNN_Critic: 2-layer SAGEConv (F: 1 -> 16 -> 1) + global_add_pool.
//
// Round-7: rounds 5/6 proved the bottleneck is neither gather addressing nor
// occupancy: every edge-scale pass costs ~35us regardless of internals, i.e.
// the per-edge LDS atomicAdd (ring-insert or bin) is the per-pass floor and
// total time ~= (#edge passes) x 35us + overhead. This round goes to the
// algorithmic minimum of TWO edge passes (layer-1 aggregate, layer-2
// aggregate -- the relu dependency makes 2 the floor) with the cheapest
// per-edge op available: one coalesced edge read, one random L2-resident 4B
// gather, one packed-integer GLOBAL atomicAdd into acc[dst] (800KB range,
// L2-resident; integer adds commute -> bit-exact vs previous rounds'
// packing). Partition/subpart/bin machinery, pairs arrays (~100MB traffic)
// and 3 kernel launches are deleted outright.

#define CNT_ONE   (1u << 25)    // count field bits [31:25] (max deg 127)
#define FX_BIAS   131072        // 2^17 per-add bias keeps sum field positive
#define SCALE     4096.0f       // 2^12 fixed-point scale
#define INV_SCALE (1.0f / 4096.0f)

// ---------------------------------------------------------------------------
// Edge pass 1: acc1[dst] += pack(count=1, fix(x[src])). 4 edges/thread.
__global__ __launch_bounds__(256) void edge1_kernel(
    const int* __restrict__ ei, const float* __restrict__ x,
    unsigned* __restrict__ acc1, int E) {
    int t = blockIdx.x * blockDim.x + threadIdx.x;
    int e0 = t * 4;
    if (e0 + 4 <= E) {
        int4 s = *(const int4*)(ei + e0);
        int4 d = *(const int4*)(ei + E + e0);
        unsigned w0 = CNT_ONE + (unsigned)((int)rintf(x[s.x] * SCALE) + FX_BIAS);
        unsigned w1 = CNT_ONE + (unsigned)((int)rintf(x[s.y] * SCALE) + FX_BIAS);
        unsigned w2 = CNT_ONE + (unsigned)((int)rintf(x[s.z] * SCALE) + FX_BIAS);
        unsigned w3 = CNT_ONE + (unsigned)((int)rintf(x[s.w] * SCALE) + FX_BIAS);
        atomicAdd(&acc1[d.x], w0);
        atomicAdd(&acc1[d.y], w1);
        atomicAdd(&acc1[d.z], w2);
        atomicAdd(&acc1[d.w], w3);
    } else {
        for (int e = e0; e < E; ++e) {
            int s = ei[e], d = ei[E + e];
            atomicAdd(&acc1[d],
                      CNT_ONE + (unsigned)((int)rintf(x[s] * SCALE) + FX_BIAS));
        }
    }
}

// ---------------------------------------------------------------------------
// Edge pass 2: acc2[dst] += fix(pv[src])  (signed i32)
__global__ __launch_bounds__(256) void edge2_kernel(
    const int* __restrict__ ei, const float* __restrict__ pv,
    int* __restrict__ acc2, int E) {
    int t = blockIdx.x * blockDim.x + threadIdx.x;
    int e0 = t * 4;
    if (e0 + 4 <= E) {
        int4 s = *(const int4*)(ei + e0);
        int4 d = *(const int4*)(ei + E + e0);
        int v0 = (int)rintf(pv[s.x] * SCALE);
        int v1 = (int)rintf(pv[s.y] * SCALE);
        int v2 = (int)rintf(pv[s.z] * SCALE);
        int v3 = (int)rintf(pv[s.w] * SCALE);
        atomicAdd(&acc2[d.x], v0);
        atomicAdd(&acc2[d.y], v1);
        atomicAdd(&acc2[d.z], v2);
        atomicAdd(&acc2[d.w], v3);
    } else {
        for (int e = e0; e < E; ++e) {
            int s = ei[e], d = ei[E + e];
            atomicAdd(&acc2[d], (int)rintf(pv[s] * SCALE));
        }
    }
}

// ---------------------------------------------------------------------------
// Node pass 1: acc1[n] -> (deg, sum1); h = relu(mean*W1l + b1 + x*W1r);
// p = h.W2l, q = h.W2r.
__global__ void node_pass1_kernel(const float* __restrict__ x,
                                  const unsigned* __restrict__ acc1,
                                  const float* __restrict__ W1l,
                                  const float* __restrict__ b1,
                                  const float* __restrict__ W1r,
                                  const float* __restrict__ W2l,
                                  const float* __restrict__ W2r,
                                  float* __restrict__ deg_out,
                                  float* __restrict__ pv,
                                  float* __restrict__ qv,
                                  int N) {
    __shared__ float s_w1l[16], s_b1[16], s_w1r[16], s_w2l[16], s_w2r[16];
    if (threadIdx.x < 16) {
        s_w1l[threadIdx.x] = W1l[threadIdx.x];
        s_b1[threadIdx.x]  = b1[threadIdx.x];
        s_w1r[threadIdx.x] = W1r[threadIdx.x];
        s_w2l[threadIdx.x] = W2l[threadIdx.x];
        s_w2r[threadIdx.x] = W2r[threadIdx.x];
    }
    __syncthreads();
    int n = blockIdx.x * blockDim.x + threadIdx.x;
    if (n >= N) return;

    unsigned w = acc1[n];
    unsigned cnt = w >> 25;
    unsigned fx  = w & (CNT_ONE - 1);
    float dg  = (float)cnt;
    float sum = (float)(int)(fx - cnt * (unsigned)FX_BIAS) * INV_SCALE;
    float m   = sum / fmaxf(dg, 1.0f);

    float xv = x[n];
    float pa = 0.0f, qa = 0.0f;
#pragma unroll
    for (int f = 0; f < 16; ++f) {
        float h = fmaf(m, s_w1l[f], fmaf(xv, s_w1r[f], s_b1[f]));
        h = fmaxf(h, 0.0f);
        pa = fmaf(h, s_w2l[f], pa);
        qa = fmaf(h, s_w2r[f], qa);
    }
    deg_out[n] = dg;
    pv[n] = pa;
    qv[n] = qa;
}

// ---------------------------------------------------------------------------
// Node pass 2 + pool: h2 = acc2[n]/max(deg,1) + b2 + q; out[batch[n]] += h2.
__global__ void node_pass2_kernel(const int* __restrict__ acc2,
                                  const float* __restrict__ deg,
                                  const float* __restrict__ qv,
                                  const float* __restrict__ b2,
                                  const int* __restrict__ batch,
                                  float* __restrict__ out,
                                  int N) {
    int i = blockIdx.x * blockDim.x + threadIdx.x;
    float b2v = b2[0];
    float val = 0.0f;
    int g;
    if (i < N) {
        float s2 = (float)acc2[i] * INV_SCALE;
        val = s2 / fmaxf(deg[i], 1.0f) + b2v + qv[i];
        g = batch[i];
    } else {
        g = batch[N - 1];  // pad lanes contribute 0 to a valid graph id
    }
    int g0 = __shfl(g, 0);
    unsigned long long same = __ballot(g == g0);
    if (same == ~0ULL) {
        for (int off = 32; off > 0; off >>= 1) val += __shfl_down(val, off);
        if ((threadIdx.x & 63) == 0) atomicAdd(&out[g0], val);
    } else {
        atomicAdd(&out[g], val);
    }
}

// ---------------------------------------------------------------------------
extern "C" void kernel_launch(void* const* d_in, const int* in_sizes, int n_in,
                              void* d_out, int out_size, void* d_ws, size_t ws_size,
                              hipStream_t stream) {
    const float* x     = (const float*)d_in[0];
    const int*   ei    = (const int*)d_in[1];   // [2, E] flat: src then dst
    const int*   batch = (const int*)d_in[2];
    const float* W1l = (const float*)d_in[4];
    const float* b1  = (const float*)d_in[5];
    const float* W1r = (const float*)d_in[6];
    const float* W2l = (const float*)d_in[7];
    const float* b2  = (const float*)d_in[8];
    const float* W2r = (const float*)d_in[9];

    const int N = in_sizes[0];        // 200000
    const int E = in_sizes[1] / 2;    // 6400000
    float* out = (float*)d_out;       // [512]

    // workspace (u32 words): acc1[N] | acc2[N] | deg[N] | pv[N] | qv[N]
    unsigned* acc1 = (unsigned*)d_ws;
    int*      acc2 = (int*)(acc1 + N);
    float* deg = (float*)(acc2 + N);
    float* pv  = deg + N;
    float* qv  = pv + N;

    hipMemsetAsync(d_out, 0, (size_t)out_size * sizeof(float), stream);
    hipMemsetAsync(acc1, 0, (size_t)(2 * N) * 4, stream);   // acc1 + acc2

    const int EB = 256;
    int edge_blocks = (E / 4 + EB - 1) / EB;    // 6250
    const int NB = 256;
    int node_blocks = (N + NB - 1) / NB;

    edge1_kernel<<<edge_blocks, EB, 0, stream>>>(ei, x, acc1, E);
    node_pass1_kernel<<<node_blocks, NB, 0, stream>>>(x, acc1, W1l, b1, W1r,
                                                      W2l, W2r, deg, pv, qv, N);
    edge2_kernel<<<edge_blocks, EB, 0, stream>>>(ei, pv, acc2, E);
    node_pass2_kernel<<<node_blocks, NB, 0, stream>>>(acc2, deg, qv, b2, batch,
                                                      out, N);
}

// Round 4
// 243.611 us; speedup vs baseline: 2.5533x; 2.5533x over previous
//
#include <hip/hip_runtime.h>

// GNN_Critic: 2-layer SAGEConv (F: 1 -> 16 -> 1) + global_add_pool.
//
// Round-8: round-7 proved random GLOBAL atomics are memory-side (per-line
// RMW, 250us/pass) -> LDS binning is mandatory. Rounds 5/6 proved the LDS
// bin passes are VALU-ISSUE-bound (~9 instr/edge ~= 45us/pass), not gather/
// occupancy bound. This round cuts instructions per edge:
//   - payloads pre-quantized per NODE (xq1[n] packed count+fix(x); pvq[n]
//     from node-pass-1) -> bin loops are load/gather/ds_add only
//   - power-of-2 partition (part = dst>>14, 13 parts x 16384 bins) kills
//     the magic-div + fixup chain in the partition pass
//   - bins flush with COALESCED global atomics into acc[N] (round-6's
//     proven-cheap flush; slab round-trips deleted)
// Integer adds commute -> bit-exact with all previous accepted rounds.
// Assumes N <= 16*16384 = 262144 (problem: N = 200000 -> 13 parts).

#define BLK       1024
#define SCAP      1024u         // partition ring capacity per part (u32)
#define SMASK     1023u
#define TILE      (BLK * 4)     // 4096 edges per partition block
#define BSH       14
#define BINS      16384
#define BMSK      16383u
#define CBIN      39            // chunks per part: 13*39 = 507 blocks ~ 2/CU
#define CNT_ONE   (1u << 25)    // count field bits [31:25]
#define FX_BIAS   131072        // 2^17 per-add bias keeps sum field positive
#define SCALE     4096.0f       // 2^12 fixed-point scale
#define INV_SCALE (1.0f / 4096.0f)

// ---------------------------------------------------------------------------
// Pre-quantize pass-1 payload: xq1[n] = CNT_ONE + (fix(x[n]) + FX_BIAS).
__global__ __launch_bounds__(256) void prequant_kernel(
    const float* __restrict__ x, unsigned* __restrict__ xq1, int N) {
    int n = blockIdx.x * blockDim.x + threadIdx.x;
    if (n < N)
        xq1[n] = CNT_ONE + (unsigned)((int)rintf(x[n] * SCALE) + FX_BIAS);
}

// ---------------------------------------------------------------------------
// Counting partition by dst-part (pow2 split). Stage packed words in
// per-part LDS rings, drain coalesced with one tail-atomic per part.
__global__ __launch_bounds__(BLK) void partition_kernel(
    const int* __restrict__ ei, unsigned* __restrict__ pairs,
    unsigned* __restrict__ tails, int E, int cap, int pp) {
    extern __shared__ unsigned buf[];                 // [pp][SCAP]
    __shared__ unsigned cnt[16], base[16], fq[16], gb[16];
    const int tid = threadIdx.x;
    if (tid < pp) { cnt[tid] = 0; base[tid] = 0; }
    __syncthreads();

    int b0 = blockIdx.x * TILE;
    int e0 = b0 + tid * 4;
    int nv = E - e0; nv = nv < 0 ? 0 : (nv > 4 ? 4 : nv);
    int srcv[4], dstv[4];
    if (nv == 4 && ((E & 3) == 0)) {
        int4 s = *(const int4*)(ei + e0);
        int4 d = *(const int4*)(ei + E + e0);
        srcv[0] = s.x; srcv[1] = s.y; srcv[2] = s.z; srcv[3] = s.w;
        dstv[0] = d.x; dstv[1] = d.y; dstv[2] = d.z; dstv[3] = d.w;
    } else {
        for (int j = 0; j < nv; ++j) { srcv[j] = ei[e0 + j]; dstv[j] = ei[E + e0 + j]; }
    }
    unsigned w[4]; int part[4]; bool pend[4];
    for (int j = 0; j < 4; ++j) {
        pend[j] = (j < nv);
        if (pend[j]) {
            unsigned dst = (unsigned)dstv[j];
            part[j] = (int)(dst >> BSH);
            w[j] = ((unsigned)srcv[j] << BSH) | (dst & BMSK);
        }
    }
    for (int j = 0; j < 4; ++j) {
        if (pend[j]) {
            unsigned slot = atomicAdd(&cnt[part[j]], 1u);
            if (slot - base[part[j]] < SCAP) {
                buf[part[j] * SCAP + (slot & SMASK)] = w[j]; pend[j] = false;
            } else atomicSub(&cnt[part[j]], 1u);
        }
    }
    int npend = __syncthreads_count((int)(pend[0] | pend[1] | pend[2] | pend[3]));
    while (npend > 0) {
        if (tid < pp) {
            unsigned avail = cnt[tid] - base[tid];
            unsigned f = avail & ~511u;
            fq[tid] = f;
            if (f) gb[tid] = atomicAdd(&tails[tid], f);
        }
        __syncthreads();
        {
            int wv = tid >> 6, lane = tid & 63;
            if (wv < pp) {
                unsigned f = fq[wv];
                if (f) {
                    unsigned g0 = gb[wv], bs = base[wv];
                    unsigned mx = (g0 + f <= (unsigned)cap) ? f : ((unsigned)cap > g0 ? (unsigned)cap - g0 : 0u);
                    unsigned* dp = pairs + (size_t)wv * cap + g0;
                    for (unsigned jj = lane; jj < mx; jj += 64)
                        dp[jj] = buf[wv * SCAP + ((bs + jj) & SMASK)];
                }
            }
        }
        __syncthreads();
        if (tid < pp) base[tid] += fq[tid];
        __syncthreads();
        for (int j = 0; j < 4; ++j) {
            if (pend[j]) {
                unsigned slot = atomicAdd(&cnt[part[j]], 1u);
                if (slot - base[part[j]] < SCAP) {
                    buf[part[j] * SCAP + (slot & SMASK)] = w[j]; pend[j] = false;
                } else atomicSub(&cnt[part[j]], 1u);
            }
        }
        npend = __syncthreads_count((int)(pend[0] | pend[1] | pend[2] | pend[3]));
    }
    if (tid < pp) {
        unsigned avail = cnt[tid] - base[tid];
        fq[tid] = avail;
        if (avail) gb[tid] = atomicAdd(&tails[tid], avail);
    }
    __syncthreads();
    {
        int wv = tid >> 6, lane = tid & 63;
        if (wv < pp) {
            unsigned f = fq[wv];
            if (f) {
                unsigned g0 = gb[wv], bs = base[wv];
                unsigned mx = (g0 + f <= (unsigned)cap) ? f : ((unsigned)cap > g0 ? (unsigned)cap - g0 : 0u);
                unsigned* dp = pairs + (size_t)wv * cap + g0;
                for (unsigned jj = lane; jj < mx; jj += 64)
                    dp[jj] = buf[wv * SCAP + ((bs + jj) & SMASK)];
            }
        }
    }
}

// ---------------------------------------------------------------------------
// Bin pass 1: sbn[ld] += xq1[src] (pre-packed); coalesced-atomic flush.
__global__ __launch_bounds__(BLK, 8) void bin1_kernel(
    const unsigned* __restrict__ pairs, const unsigned* __restrict__ tails,
    const unsigned* __restrict__ xq1, unsigned* __restrict__ acc1,
    int N, int cap) {
    extern __shared__ unsigned sbn[];                 // [BINS] = 64 KB
    const int tid = threadIdx.x;
    const int p = blockIdx.x;
    const int c = blockIdx.y;
    for (int j = tid; j < BINS; j += BLK) sbn[j] = 0;
    __syncthreads();
    int len = (int)tails[p]; if (len > cap) len = cap;
    int st = (int)((long long)len * c / CBIN);
    int en = (int)((long long)len * (c + 1) / CBIN);
    const unsigned* bp = pairs + (size_t)p * cap;
    int st4 = (st + 3) & ~3;
    int en4 = en & ~3;
    int preEnd = st4 < en ? st4 : en;
    for (int e = st + tid; e < preEnd; e += BLK) {
        unsigned wv = bp[e];
        atomicAdd(&sbn[wv & BMSK], xq1[wv >> BSH]);
    }
    if (st4 < en4) {
        const uint4* bp4 = (const uint4*)(bp + st4);
        int n4 = (en4 - st4) >> 2;
        for (int e = tid; e < n4; e += BLK) {
            uint4 wq = bp4[e];
            unsigned p0 = xq1[wq.x >> BSH];
            unsigned p1 = xq1[wq.y >> BSH];
            unsigned p2 = xq1[wq.z >> BSH];
            unsigned p3 = xq1[wq.w >> BSH];
            atomicAdd(&sbn[wq.x & BMSK], p0);
            atomicAdd(&sbn[wq.y & BMSK], p1);
            atomicAdd(&sbn[wq.z & BMSK], p2);
            atomicAdd(&sbn[wq.w & BMSK], p3);
        }
    }
    int tailSt = st4 > en4 ? st4 : en4;
    for (int e = tailSt + tid; e < en; e += BLK) {
        unsigned wv = bp[e];
        atomicAdd(&sbn[wv & BMSK], xq1[wv >> BSH]);
    }
    __syncthreads();
    unsigned* dst = acc1 + ((size_t)p << BSH);
    int nb = N - (p << BSH); if (nb > BINS) nb = BINS;
    for (int j = tid; j < nb; j += BLK) {
        unsigned v = sbn[j];
        if (v) atomicAdd(&dst[j], v);    // coalesced: cheap (round-6/7 model)
    }
}

// ---------------------------------------------------------------------------
// Bin pass 2: sbi[ld] += pvq[src] (signed, pre-quantized); coalesced flush.
__global__ __launch_bounds__(BLK, 8) void bin2_kernel(
    const unsigned* __restrict__ pairs, const unsigned* __restrict__ tails,
    const int* __restrict__ pvq, int* __restrict__ acc2,
    int N, int cap) {
    extern __shared__ int sbi[];                      // [BINS] = 64 KB
    const int tid = threadIdx.x;
    const int p = blockIdx.x;
    const int c = blockIdx.y;
    for (int j = tid; j < BINS; j += BLK) sbi[j] = 0;
    __syncthreads();
    int len = (int)tails[p]; if (len > cap) len = cap;
    int st = (int)((long long)len * c / CBIN);
    int en = (int)((long long)len * (c + 1) / CBIN);
    const unsigned* bp = pairs + (size_t)p * cap;
    int st4 = (st + 3) & ~3;
    int en4 = en & ~3;
    int preEnd = st4 < en ? st4 : en;
    for (int e = st + tid; e < preEnd; e += BLK) {
        unsigned wv = bp[e];
        atomicAdd(&sbi[wv & BMSK], pvq[wv >> BSH]);
    }
    if (st4 < en4) {
        const uint4* bp4 = (const uint4*)(bp + st4);
        int n4 = (en4 - st4) >> 2;
        for (int e = tid; e < n4; e += BLK) {
            uint4 wq = bp4[e];
            int p0 = pvq[wq.x >> BSH];
            int p1 = pvq[wq.y >> BSH];
            int p2 = pvq[wq.z >> BSH];
            int p3 = pvq[wq.w >> BSH];
            atomicAdd(&sbi[wq.x & BMSK], p0);
            atomicAdd(&sbi[wq.y & BMSK], p1);
            atomicAdd(&sbi[wq.z & BMSK], p2);
            atomicAdd(&sbi[wq.w & BMSK], p3);
        }
    }
    int tailSt = st4 > en4 ? st4 : en4;
    for (int e = tailSt + tid; e < en; e += BLK) {
        unsigned wv = bp[e];
        atomicAdd(&sbi[wv & BMSK], pvq[wv >> BSH]);
    }
    __syncthreads();
    int* dst = acc2 + ((size_t)p << BSH);
    int nb = N - (p << BSH); if (nb > BINS) nb = BINS;
    for (int j = tid; j < nb; j += BLK) {
        int v = sbi[j];
        if (v) atomicAdd(&dst[j], v);
    }
}

// ---------------------------------------------------------------------------
// Node pass 1: acc1[n] -> (deg, sum1); h = relu(mean*W1l + b1 + x*W1r);
// pvq = fix(h.W2l) pre-quantized for bin2; q = h.W2r.
__global__ void node_pass1_kernel(const float* __restrict__ x,
                                  const unsigned* __restrict__ acc1,
                                  const float* __restrict__ W1l,
                                  const float* __restrict__ b1,
                                  const float* __restrict__ W1r,
                                  const float* __restrict__ W2l,
                                  const float* __restrict__ W2r,
                                  float* __restrict__ deg_out,
                                  int* __restrict__ pvq,
                                  float* __restrict__ qv,
                                  int N) {
    __shared__ float s_w1l[16], s_b1[16], s_w1r[16], s_w2l[16], s_w2r[16];
    if (threadIdx.x < 16) {
        s_w1l[threadIdx.x] = W1l[threadIdx.x];
        s_b1[threadIdx.x]  = b1[threadIdx.x];
        s_w1r[threadIdx.x] = W1r[threadIdx.x];
        s_w2l[threadIdx.x] = W2l[threadIdx.x];
        s_w2r[threadIdx.x] = W2r[threadIdx.x];
    }
    __syncthreads();
    int n = blockIdx.x * blockDim.x + threadIdx.x;
    if (n >= N) return;

    unsigned w = acc1[n];
    unsigned cnt = w >> 25;
    unsigned fx  = w & (CNT_ONE - 1);
    float dg  = (float)cnt;
    float sum = (float)(int)(fx - cnt * (unsigned)FX_BIAS) * INV_SCALE;
    float m   = sum / fmaxf(dg, 1.0f);

    float xv = x[n];
    float pa = 0.0f, qa = 0.0f;
#pragma unroll
    for (int f = 0; f < 16; ++f) {
        float h = fmaf(m, s_w1l[f], fmaf(xv, s_w1r[f], s_b1[f]));
        h = fmaxf(h, 0.0f);
        pa = fmaf(h, s_w2l[f], pa);
        qa = fmaf(h, s_w2r[f], qa);
    }
    deg_out[n] = dg;
    pvq[n] = (int)rintf(pa * SCALE);
    qv[n] = qa;
}

// ---------------------------------------------------------------------------
// Node pass 2 + pool: h2 = acc2[n]/max(deg,1) + b2 + q; out[batch[n]] += h2.
__global__ void node_pass2_kernel(const int* __restrict__ acc2,
                                  const float* __restrict__ deg,
                                  const float* __restrict__ qv,
                                  const float* __restrict__ b2,
                                  const int* __restrict__ batch,
                                  float* __restrict__ out,
                                  int N) {
    int i = blockIdx.x * blockDim.x + threadIdx.x;
    float b2v = b2[0];
    float val = 0.0f;
    int g;
    if (i < N) {
        float s2 = (float)acc2[i] * INV_SCALE;
        val = s2 / fmaxf(deg[i], 1.0f) + b2v + qv[i];
        g = batch[i];
    } else {
        g = batch[N - 1];  // pad lanes contribute 0 to a valid graph id
    }
    int g0 = __shfl(g, 0);
    unsigned long long same = __ballot(g == g0);
    if (same == ~0ULL) {
        for (int off = 32; off > 0; off >>= 1) val += __shfl_down(val, off);
        if ((threadIdx.x & 63) == 0) atomicAdd(&out[g0], val);
    } else {
        atomicAdd(&out[g], val);
    }
}

// ---------------------------------------------------------------------------
extern "C" void kernel_launch(void* const* d_in, const int* in_sizes, int n_in,
                              void* d_out, int out_size, void* d_ws, size_t ws_size,
                              hipStream_t stream) {
    const float* x     = (const float*)d_in[0];
    const int*   ei    = (const int*)d_in[1];   // [2, E] flat: src then dst
    const int*   batch = (const int*)d_in[2];
    const float* W1l = (const float*)d_in[4];
    const float* b1  = (const float*)d_in[5];
    const float* W1r = (const float*)d_in[6];
    const float* W2l = (const float*)d_in[7];
    const float* b2  = (const float*)d_in[8];
    const float* W2r = (const float*)d_in[9];

    const int N = in_sizes[0];        // 200000
    const int E = in_sizes[1] / 2;    // 6400000
    float* out = (float*)d_out;       // [512]

    const int pp = (N + BINS - 1) >> BSH;                 // 13
    // max expected edges per (full) part + ~47-sigma margin, 1KB-aligned
    long long expMax = ((long long)E * BINS + N - 1) / N; // 524288
    int cap = (int)((expMax + 32768 + 1023) & ~1023LL);

    // workspace (u32 words):
    // pairs[pp][cap] | acc1[N] | acc2[N] | tails[16] | xq1[N] |
    // deg[N] (f32) | pvq[N] (i32) | qv[N] (f32)
    unsigned* pairs = (unsigned*)d_ws;
    unsigned* acc1  = pairs + (size_t)pp * cap;
    int*      acc2  = (int*)(acc1 + N);
    unsigned* tails = (unsigned*)(acc2 + N);
    unsigned* xq1   = tails + 16;
    float* deg = (float*)(xq1 + N);
    int*   pvq = (int*)(deg + N);
    float* qv  = (float*)(pvq + N);

    hipMemsetAsync(d_out, 0, (size_t)out_size * sizeof(float), stream);
    hipMemsetAsync(acc1, 0, (size_t)(2 * N + 16) * 4, stream);  // acc1|acc2|tails

    const int partShmem = pp * (int)SCAP * 4;           // 53248 B
    const int binShmem  = BINS * 4;                     // 65536 B
    hipFuncSetAttribute((const void*)partition_kernel,
                        hipFuncAttributeMaxDynamicSharedMemorySize, partShmem);
    hipFuncSetAttribute((const void*)bin1_kernel,
                        hipFuncAttributeMaxDynamicSharedMemorySize, binShmem);
    hipFuncSetAttribute((const void*)bin2_kernel,
                        hipFuncAttributeMaxDynamicSharedMemorySize, binShmem);

    int partBlocks = (E + TILE - 1) / TILE;     // 1563
    const int NB = 256;
    int node_blocks = (N + NB - 1) / NB;

    prequant_kernel<<<node_blocks, NB, 0, stream>>>(x, xq1, N);
    partition_kernel<<<partBlocks, BLK, partShmem, stream>>>(ei, pairs, tails,
                                                             E, cap, pp);
    bin1_kernel<<<dim3(pp, CBIN), BLK, binShmem, stream>>>(pairs, tails, xq1,
                                                           acc1, N, cap);
    node_pass1_kernel<<<node_blocks, NB, 0, stream>>>(x, acc1, W1l, b1, W1r,
                                                      W2l, W2r, deg, pvq, qv, N);
    bin2_kernel<<<dim3(pp, CBIN), BLK, binShmem, stream>>>(pairs, tails, pvq,
                                                           acc2, N, cap);
    node_pass2_kernel<<<node_blocks, NB, 0, stream>>>(acc2, deg, qv, b2, batch,
                                                      out, N);
}

// Round 6
// 219.831 us; speedup vs baseline: 2.8295x; 1.1082x over previous
//
#include <hip/hip_runtime.h>

// GNN_Critic: 2-layer SAGEConv (F: 1 -> 16 -> 1) + global_add_pool.
//
// Round-10: recovery round. Round-9's 325-cell partition failed correctness;
// reverted to the proven round-4-lineage structure (222.3us: magic-div
// 16-part partition, 50KB LDS bins, CBIN=16 slab stores, node-side slab
// reduce). Only verified-safe trims applied on top:
//   - payload pre-quantization: xq1[n] (packed count|fix(x)) computed in a
//     prologue of the partition kernel (also saves one launch); node-pass-1
//     emits pvq[n] = fix(p[n]) directly. Bin inner loops become pure
//     load/gather/ds_add (no rintf/pack chain per edge).
// Integer bin sums commute -> bit-exact with the accepted rounds.

#define PP        16            // node parts / buckets
#define BLK       1024
#define SCAP      1024u         // per-part LDS staging ring capacity (u32)
#define SMASK     1023u
#define TILE      (BLK * 4)     // 4096 edges per partition block
#define CBIN      16            // slab chunks per part
#define CNT_ONE   (1u << 25)    // pass-1 count field bits [31:25]
#define FX_BIAS   131072        // 2^17 per-add bias keeps sum field positive
#define SCALE     4096.0f      // 2^12 fixed-point scale
#define INV_SCALE (1.0f / 4096.0f)

// ---------------------------------------------------------------------------
// Counting partition: one tile of 4096 edges per block. Stage packed words in
// per-part LDS rings, drain coalesced with one tail-atomic per part.
// Prologue: pre-quantize x into xq1 (disjoint slices per block).
__global__ __launch_bounds__(BLK) void partition_kernel(
    const int* __restrict__ ei, const float* __restrict__ x,
    unsigned* __restrict__ xq1, unsigned* __restrict__ pairs,
    unsigned* __restrict__ tails, int E, int N, int bins, unsigned Mdiv,
    int cap) {
    extern __shared__ unsigned buf[];                 // [PP][SCAP] = 64 KB
    __shared__ unsigned cnt[PP], base[PP], fq[PP], gb[PP];
    const int tid = threadIdx.x;
    if (tid < PP) { cnt[tid] = 0; base[tid] = 0; }

    // pre-quantize payload for bin1 (grid covers N in one stride)
    for (int n = blockIdx.x * BLK + tid; n < N; n += gridDim.x * BLK)
        xq1[n] = CNT_ONE + (unsigned)((int)rintf(x[n] * SCALE) + FX_BIAS);
    __syncthreads();

    int b0 = blockIdx.x * TILE;
    int e0 = b0 + tid * 4;
    int nv = E - e0; nv = nv < 0 ? 0 : (nv > 4 ? 4 : nv);
    int srcv[4], dstv[4];
    if (nv == 4 && ((E & 3) == 0)) {
        int4 s = *(const int4*)(ei + e0);
        int4 d = *(const int4*)(ei + E + e0);
        srcv[0] = s.x; srcv[1] = s.y; srcv[2] = s.z; srcv[3] = s.w;
        dstv[0] = d.x; dstv[1] = d.y; dstv[2] = d.z; dstv[3] = d.w;
    } else {
        for (int j = 0; j < nv; ++j) { srcv[j] = ei[e0 + j]; dstv[j] = ei[E + e0 + j]; }
    }
    unsigned w[4]; int part[4]; bool pend[4];
    for (int j = 0; j < 4; ++j) {
        pend[j] = (j < nv);
        if (pend[j]) {
            unsigned dst = (unsigned)dstv[j];
            unsigned pt = (unsigned)(((unsigned long long)dst * Mdiv) >> 32);
            int ld = (int)dst - (int)pt * bins;
            while (ld >= bins) { ld -= bins; ++pt; }
            while (ld < 0)     { ld += bins; --pt; }
            part[j] = (int)pt;
            w[j] = ((unsigned)srcv[j] << 14) | (unsigned)ld;
        }
    }
    // insertion (overflow cannot occur for random input; retry loop is the
    // correctness guarantee for pathological part skew)
    for (int j = 0; j < 4; ++j) {
        if (pend[j]) {
            unsigned slot = atomicAdd(&cnt[part[j]], 1u);
            if (slot - base[part[j]] < SCAP) {
                buf[part[j] * SCAP + (slot & SMASK)] = w[j]; pend[j] = false;
            } else atomicSub(&cnt[part[j]], 1u);
        }
    }
    int npend = __syncthreads_count((int)(pend[0] | pend[1] | pend[2] | pend[3]));
    while (npend > 0) {
        if (tid < PP) {
            unsigned avail = cnt[tid] - base[tid];
            unsigned f = avail & ~511u;
            fq[tid] = f;
            if (f) gb[tid] = atomicAdd(&tails[tid], f);
        }
        __syncthreads();
        {
            int wv = tid >> 6, lane = tid & 63;
            unsigned f = fq[wv];
            if (f) {
                unsigned g0 = gb[wv], bs = base[wv];
                unsigned mx = (g0 + f <= (unsigned)cap) ? f : ((unsigned)cap > g0 ? (unsigned)cap - g0 : 0u);
                unsigned* dp = pairs + (size_t)wv * cap + g0;
                for (unsigned jj = lane; jj < mx; jj += 64)
                    dp[jj] = buf[wv * SCAP + ((bs + jj) & SMASK)];
            }
        }
        __syncthreads();
        if (tid < PP) base[tid] += fq[tid];
        __syncthreads();
        for (int j = 0; j < 4; ++j) {
            if (pend[j]) {
                unsigned slot = atomicAdd(&cnt[part[j]], 1u);
                if (slot - base[part[j]] < SCAP) {
                    buf[part[j] * SCAP + (slot & SMASK)] = w[j]; pend[j] = false;
                } else atomicSub(&cnt[part[j]], 1u);
            }
        }
        npend = __syncthreads_count((int)(pend[0] | pend[1] | pend[2] | pend[3]));
    }
    // final drain
    if (tid < PP) {
        unsigned avail = cnt[tid] - base[tid];
        fq[tid] = avail;
        if (avail) gb[tid] = atomicAdd(&tails[tid], avail);
    }
    __syncthreads();
    {
        int wv = tid >> 6, lane = tid & 63;
        unsigned f = fq[wv];
        if (f) {
            unsigned g0 = gb[wv], bs = base[wv];
            unsigned mx = (g0 + f <= (unsigned)cap) ? f : ((unsigned)cap > g0 ? (unsigned)cap - g0 : 0u);
            unsigned* dp = pairs + (size_t)wv * cap + g0;
            for (unsigned jj = lane; jj < mx; jj += 64)
                dp[jj] = buf[wv * SCAP + ((bs + jj) & SMASK)];
        }
    }
}

// ---------------------------------------------------------------------------
// Bin pass 1: bins[ld] += xq1[src] (pre-packed count|fix) over (part, chunk).
__global__ __launch_bounds__(BLK) void bin1_kernel(
    const unsigned* __restrict__ pairs, const unsigned* __restrict__ tails,
    const unsigned* __restrict__ xq1, unsigned* __restrict__ slab,
    int N, int bins, int cap) {
    extern __shared__ unsigned sb[];
    int p = blockIdx.x & (PP - 1);
    int c = blockIdx.x / PP;
    int len = (int)tails[p]; if (len > cap) len = cap;
    int st = (int)((long long)len * c / CBIN);
    int en = (int)((long long)len * (c + 1) / CBIN);
    for (int j = threadIdx.x; j < bins; j += BLK) sb[j] = 0;
    __syncthreads();
    const unsigned* bp = pairs + (size_t)p * cap;
    int st4 = (st + 3) & ~3;
    int en4 = en & ~3;
    int preEnd = st4 < en ? st4 : en;
    for (int e = st + (int)threadIdx.x; e < preEnd; e += BLK) {
        unsigned wv = bp[e];
        atomicAdd(&sb[wv & 16383u], xq1[wv >> 14]);
    }
    if (st4 < en4) {
        const uint4* bp4 = (const uint4*)(bp + st4);
        int n4 = (en4 - st4) >> 2;
        for (int e = threadIdx.x; e < n4; e += BLK) {
            uint4 wq = bp4[e];
            unsigned p0 = xq1[wq.x >> 14];
            unsigned p1 = xq1[wq.y >> 14];
            unsigned p2 = xq1[wq.z >> 14];
            unsigned p3 = xq1[wq.w >> 14];
            atomicAdd(&sb[wq.x & 16383u], p0);
            atomicAdd(&sb[wq.y & 16383u], p1);
            atomicAdd(&sb[wq.z & 16383u], p2);
            atomicAdd(&sb[wq.w & 16383u], p3);
        }
    }
    int tailSt = st4 > en4 ? st4 : en4;
    for (int e = tailSt + (int)threadIdx.x; e < en; e += BLK) {
        unsigned wv = bp[e];
        atomicAdd(&sb[wv & 16383u], xq1[wv >> 14]);
    }
    __syncthreads();
    unsigned* dst = slab + (size_t)c * N + (size_t)p * bins;
    int nb = N - p * bins; if (nb > bins) nb = bins;
    for (int j = threadIdx.x; j < nb; j += BLK) dst[j] = sb[j];
}

// ---------------------------------------------------------------------------
// Bin pass 2: bins[ld] += pvq[src]  (signed i32, pre-quantized)
__global__ __launch_bounds__(BLK) void bin2_kernel(
    const unsigned* __restrict__ pairs, const unsigned* __restrict__ tails,
    const int* __restrict__ pvq, int* __restrict__ slab,
    int N, int bins, int cap) {
    extern __shared__ int sbi[];
    int p = blockIdx.x & (PP - 1);
    int c = blockIdx.x / PP;
    int len = (int)tails[p]; if (len > cap) len = cap;
    int st = (int)((long long)len * c / CBIN);
    int en = (int)((long long)len * (c + 1) / CBIN);
    for (int j = threadIdx.x; j < bins; j += BLK) sbi[j] = 0;
    __syncthreads();
    const unsigned* bp = pairs + (size_t)p * cap;
    int st4 = (st + 3) & ~3;
    int en4 = en & ~3;
    int preEnd = st4 < en ? st4 : en;
    for (int e = st + (int)threadIdx.x; e < preEnd; e += BLK) {
        unsigned wv = bp[e];
        atomicAdd(&sbi[wv & 16383u], pvq[wv >> 14]);
    }
    if (st4 < en4) {
        const uint4* bp4 = (const uint4*)(bp + st4);
        int n4 = (en4 - st4) >> 2;
        for (int e = threadIdx.x; e < n4; e += BLK) {
            uint4 wq = bp4[e];
            int p0 = pvq[wq.x >> 14];
            int p1 = pvq[wq.y >> 14];
            int p2 = pvq[wq.z >> 14];
            int p3 = pvq[wq.w >> 14];
            atomicAdd(&sbi[wq.x & 16383u], p0);
            atomicAdd(&sbi[wq.y & 16383u], p1);
            atomicAdd(&sbi[wq.z & 16383u], p2);
            atomicAdd(&sbi[wq.w & 16383u], p3);
        }
    }
    int tailSt = st4 > en4 ? st4 : en4;
    for (int e = tailSt + (int)threadIdx.x; e < en; e += BLK) {
        unsigned wv = bp[e];
        atomicAdd(&sbi[wv & 16383u], pvq[wv >> 14]);
    }
    __syncthreads();
    int* dst = slab + (size_t)c * N + (size_t)p * bins;
    int nb = N - p * bins; if (nb > bins) nb = bins;
    for (int j = threadIdx.x; j < nb; j += BLK) dst[j] = sbi[j];
}

// ---------------------------------------------------------------------------
// Node pass 1: reduce CBIN slab entries -> (sum1, deg); compute
// h[f] = relu(mean1*W1l[f] + b1[f] + x*W1r[f]); pvq = fix(h.W2l); q = h.W2r.
__global__ void node_pass1_kernel(const float* __restrict__ x,
                                  const unsigned* __restrict__ slab,
                                  const float* __restrict__ W1l,
                                  const float* __restrict__ b1,
                                  const float* __restrict__ W1r,
                                  const float* __restrict__ W2l,
                                  const float* __restrict__ W2r,
                                  float* __restrict__ deg_out,
                                  int* __restrict__ pvq,
                                  float* __restrict__ qv,
                                  int N) {
    __shared__ float s_w1l[16], s_b1[16], s_w1r[16], s_w2l[16], s_w2r[16];
    if (threadIdx.x < 16) {
        s_w1l[threadIdx.x] = W1l[threadIdx.x];
        s_b1[threadIdx.x]  = b1[threadIdx.x];
        s_w1r[threadIdx.x] = W1r[threadIdx.x];
        s_w2l[threadIdx.x] = W2l[threadIdx.x];
        s_w2r[threadIdx.x] = W2r[threadIdx.x];
    }
    __syncthreads();
    int n = blockIdx.x * blockDim.x + threadIdx.x;
    if (n >= N) return;

    unsigned cnt = 0, fx = 0;
#pragma unroll
    for (int c = 0; c < CBIN; ++c) {
        unsigned w = slab[(size_t)c * N + n];
        cnt += w >> 25;
        fx  += w & (CNT_ONE - 1);
    }
    float dg  = (float)cnt;
    float sum = (float)(int)(fx - cnt * (unsigned)FX_BIAS) * INV_SCALE;
    float m   = sum / fmaxf(dg, 1.0f);

    float xv = x[n];
    float pa = 0.0f, qa = 0.0f;
#pragma unroll
    for (int f = 0; f < 16; ++f) {
        float h = fmaf(m, s_w1l[f], fmaf(xv, s_w1r[f], s_b1[f]));
        h = fmaxf(h, 0.0f);
        pa = fmaf(h, s_w2l[f], pa);
        qa = fmaf(h, s_w2r[f], qa);
    }
    deg_out[n] = dg;
    pvq[n] = (int)rintf(pa * SCALE);
    qv[n] = qa;
}

// ---------------------------------------------------------------------------
// Node pass 2 + pool: s2 = sum_c slab2[c][n]; h2 = s2/max(deg,1) + b2 + q;
// out[batch[n]] += h2 (batch sorted -> wave-segmented reduction).
__global__ void node_pass2_kernel(const int* __restrict__ slab2,
                                  const float* __restrict__ deg,
                                  const float* __restrict__ qv,
                                  const float* __restrict__ b2,
                                  const int* __restrict__ batch,
                                  float* __restrict__ out,
                                  int N) {
    int i = blockIdx.x * blockDim.x + threadIdx.x;
    float b2v = b2[0];
    float val = 0.0f;
    int g;
    if (i < N) {
        int sacc = 0;
#pragma unroll
        for (int c = 0; c < CBIN; ++c) sacc += slab2[(size_t)c * N + i];
        float s2 = (float)sacc * INV_SCALE;
        val = s2 / fmaxf(deg[i], 1.0f) + b2v + qv[i];
        g = batch[i];
    } else {
        g = batch[N - 1];  // pad lanes contribute 0 to a valid graph id
    }
    int g0 = __shfl(g, 0);
    unsigned long long same = __ballot(g == g0);
    if (same == ~0ULL) {
        for (int off = 32; off > 0; off >>= 1) val += __shfl_down(val, off);
        if ((threadIdx.x & 63) == 0) atomicAdd(&out[g0], val);
    } else {
        atomicAdd(&out[g], val);
    }
}

// ---------------------------------------------------------------------------
extern "C" void kernel_launch(void* const* d_in, const int* in_sizes, int n_in,
                              void* d_out, int out_size, void* d_ws, size_t ws_size,
                              hipStream_t stream) {
    const float* x     = (const float*)d_in[0];
    const int*   ei    = (const int*)d_in[1];   // [2, E] flat: src then dst
    const int*   batch = (const int*)d_in[2];
    const float* W1l = (const float*)d_in[4];
    const float* b1  = (const float*)d_in[5];
    const float* W1r = (const float*)d_in[6];
    const float* W2l = (const float*)d_in[7];
    const float* b2  = (const float*)d_in[8];
    const float* W2r = (const float*)d_in[9];

    const int N = in_sizes[0];        // 200000
    const int E = in_sizes[1] / 2;    // 6400000
    float* out = (float*)d_out;       // [512]

    const int bins = (N + PP - 1) / PP;                       // 12500
    const unsigned Mdiv =
        (unsigned)(((1ULL << 32) + (unsigned)bins - 1) / (unsigned)bins);
    const int EperP = E / PP;
    int cap = ((EperP + EperP / 32 + 4096) + 1023) & ~1023;   // ~20-sigma margin

    // workspace (u32 words): pairs[PP][cap] | slab[CBIN][N] |
    // deg (f32) | pvq (i32) | qv (f32) | tails[PP] | xq1[N]
    unsigned* pairs = (unsigned*)d_ws;
    unsigned* slab1 = pairs + (size_t)PP * cap;
    int*      slab2 = (int*)slab1;
    float* deg = (float*)(slab1 + (size_t)CBIN * N);
    int*   pvq = (int*)(deg + N);
    float* qv  = (float*)(pvq + N);
    unsigned* tails = (unsigned*)(qv + N);
    unsigned* xq1   = tails + PP;

    hipMemsetAsync(d_out, 0, (size_t)out_size * sizeof(float), stream);
    hipMemsetAsync(tails, 0, PP * sizeof(unsigned), stream);

    const int partShmem = PP * (int)SCAP * 4;   // 65536 B
    const int binShmem  = bins * 4;             // 50000 B
    hipFuncSetAttribute((const void*)partition_kernel,
                        hipFuncAttributeMaxDynamicSharedMemorySize, partShmem);
    hipFuncSetAttribute((const void*)bin1_kernel,
                        hipFuncAttributeMaxDynamicSharedMemorySize, binShmem);
    hipFuncSetAttribute((const void*)bin2_kernel,
                        hipFuncAttributeMaxDynamicSharedMemorySize, binShmem);

    int partBlocks = (E + TILE - 1) / TILE;     // 1563
    const int NB = 256;
    int node_blocks = (N + NB - 1) / NB;

    partition_kernel<<<partBlocks, BLK, partShmem, stream>>>(ei, x, xq1, pairs,
                                                             tails, E, N, bins,
                                                             Mdiv, cap);
    bin1_kernel<<<PP * CBIN, BLK, binShmem, stream>>>(pairs, tails, xq1, slab1,
                                                      N, bins, cap);
    node_pass1_kernel<<<node_blocks, NB, 0, stream>>>(x, slab1, W1l, b1, W1r,
                                                      W2l, W2r, deg, pvq, qv, N);
    bin2_kernel<<<PP * CBIN, BLK, binShmem, stream>>>(pairs, tails, pvq, slab2,
                                                      N, bins, cap);
    node_pass2_kernel<<<node_blocks, NB, 0, stream>>>(slab2, deg, qv, b2, batch,
                                                      out, N);
}